// Round 4
// baseline (504.426 us; speedup 1.0000x reference)
//
#include <hip/hip_runtime.h>
#include <hip/hip_bf16.h>
#include <stdint.h>

// Problem constants (B=4, T=2048, D=H=1024, E=8, topn=2)
#define TOKENS   8192
#define DDIM     1024
#define EXPERTS  8
#define NSLOT    (TOKENS * 2)   // every token picks exactly 2 experts
#define MAXTILE  136            // >= max sum over e of ceil(ne/128) (135)

typedef __bf16 bf16x8_t __attribute__((ext_vector_type(8)));
typedef __bf16 bf16x4_t __attribute__((ext_vector_type(4)));
typedef float  f32x4_t  __attribute__((ext_vector_type(4)));

// ---------------------------------------------------------------------------
// async global->LDS, 16B per lane; LDS dest is wave-uniform base (HW adds
// lane*16).
__device__ __forceinline__ void gl_lds16(const void* g, void* l) {
  __builtin_amdgcn_global_load_lds(
      (const __attribute__((address_space(1))) void*)g,
      (__attribute__((address_space(3))) void*)l, 16, 0, 0);
}

// ---------------------------------------------------------------------------
// Weight transpose + convert for all 3 layers: w[e][k][n] fp32 -> wT[e][n][k]
// bf16. z = 24 (layer = z>>3, expert = z&7).
__global__ void twt_k(const float* __restrict__ w1, const float* __restrict__ w2,
                      const float* __restrict__ w3, __bf16* __restrict__ w1T,
                      __bf16* __restrict__ w2T, __bf16* __restrict__ w3T) {
  __shared__ float tile[64][33];
  const int layer = blockIdx.z >> 3, e = blockIdx.z & 7;
  const float* w = (layer == 0) ? w1 : (layer == 1) ? w2 : w3;
  __bf16* wT = (layer == 0) ? w1T : (layer == 1) ? w2T : w3T;
  const int kb = blockIdx.x * 64, nb = blockIdx.y * 32;
  const size_t ebase = (size_t)e << 20;  // e * 1024*1024
  const int tx = threadIdx.x, ty = threadIdx.y;  // 32 x 8
  const float* src = w + ebase;
#pragma unroll
  for (int r = ty; r < 64; r += 8)
    tile[r][tx] = src[(size_t)(kb + r) * 1024 + nb + tx];
  __syncthreads();
  __bf16* dst = wT + ebase;
#pragma unroll
  for (int r = ty; r < 32; r += 8) {
    union { __bf16 h[2]; unsigned u; } pk;
    pk.h[0] = (__bf16)tile[2 * tx][r];
    pk.h[1] = (__bf16)tile[2 * tx + 1][r];
    *(unsigned*)(dst + (size_t)(nb + r) * 1024 + kb + 2 * tx) = pk.u;
  }
}

// ---------------------------------------------------------------------------
// Gating + x->bf16 convert fused: one wave per token, no atomics.
// Weights = softmax over the two top logits (L1-renorm cancels denominator).
__global__ __launch_bounds__(256) void gate_k(
    const float* __restrict__ x, const float* __restrict__ gw,
    const float* __restrict__ gb, __bf16* __restrict__ xbf,
    int* __restrict__ top_i, float* __restrict__ top_w) {
  const int t = blockIdx.x * 4 + (threadIdx.x >> 6);
  const int lane = threadIdx.x & 63;
  const float4* x4 = (const float4*)(x + (size_t)t * DDIM);
  bf16x4_t* xo4 = (bf16x4_t*)(xbf + (size_t)t * DDIM);
  const float4* g4 = (const float4*)gw;
  float acc[EXPERTS];
#pragma unroll
  for (int e = 0; e < EXPERTS; ++e) acc[e] = 0.f;
#pragma unroll
  for (int d4 = lane; d4 < 256; d4 += 64) {
    const float4 v = x4[d4];
    bf16x4_t o = {(__bf16)v.x, (__bf16)v.y, (__bf16)v.z, (__bf16)v.w};
    xo4[d4] = o;
    const float4* g = g4 + (size_t)d4 * 8;  // rows 4*d4..4*d4+3, 2 float4 each
    float4 ga, gbv;
    ga = g[0]; gbv = g[1];
    acc[0] += v.x * ga.x; acc[1] += v.x * ga.y; acc[2] += v.x * ga.z; acc[3] += v.x * ga.w;
    acc[4] += v.x * gbv.x; acc[5] += v.x * gbv.y; acc[6] += v.x * gbv.z; acc[7] += v.x * gbv.w;
    ga = g[2]; gbv = g[3];
    acc[0] += v.y * ga.x; acc[1] += v.y * ga.y; acc[2] += v.y * ga.z; acc[3] += v.y * ga.w;
    acc[4] += v.y * gbv.x; acc[5] += v.y * gbv.y; acc[6] += v.y * gbv.z; acc[7] += v.y * gbv.w;
    ga = g[4]; gbv = g[5];
    acc[0] += v.z * ga.x; acc[1] += v.z * ga.y; acc[2] += v.z * ga.z; acc[3] += v.z * ga.w;
    acc[4] += v.z * gbv.x; acc[5] += v.z * gbv.y; acc[6] += v.z * gbv.z; acc[7] += v.z * gbv.w;
    ga = g[6]; gbv = g[7];
    acc[0] += v.w * ga.x; acc[1] += v.w * ga.y; acc[2] += v.w * ga.z; acc[3] += v.w * ga.w;
    acc[4] += v.w * gbv.x; acc[5] += v.w * gbv.y; acc[6] += v.w * gbv.z; acc[7] += v.w * gbv.w;
  }
#pragma unroll
  for (int e = 0; e < EXPERTS; ++e)
    for (int s = 32; s > 0; s >>= 1) acc[e] += __shfl_down(acc[e], s);
  if (lane == 0) {
#pragma unroll
    for (int e = 0; e < EXPERTS; ++e) acc[e] += gb[e];
    int i1 = 0;
    for (int e = 1; e < EXPERTS; ++e)
      if (acc[e] > acc[i1]) i1 = e;
    int i2 = (i1 == 0) ? 1 : 0;
    for (int e = 0; e < EXPERTS; ++e)
      if (e != i1 && acc[e] > acc[i2]) i2 = e;
    const float r = expf(acc[i2] - acc[i1]);  // <= 1
    const float wA = 1.f / (1.f + r);
    const float wB = r / (1.f + r);
    top_i[t * 2] = i1; top_i[t * 2 + 1] = i2;
    top_w[t * 2] = wA; top_w[t * 2 + 1] = wB;
  }
}

// ---------------------------------------------------------------------------
// Routing plan: ONE block, 1024 threads. Stable counting-sort of the 16384
// (token,expert) entries; zero global atomics, deterministic. Also emits the
// exact GEMM tile work-list ((e,mtile) pairs) and per-slot combine weights.
__global__ __launch_bounds__(1024) void plan_k(
    const int* __restrict__ top_i, const float* __restrict__ top_w,
    int* __restrict__ eoff, int* __restrict__ tok_list,
    int* __restrict__ slot_of, float* __restrict__ slot_w,
    int* __restrict__ work, int* __restrict__ ntiles) {
  const int tid = threadIdx.x;
  const int lane = tid & 63, wid = tid >> 6;  // 16 waves
  __shared__ int ws[16][EXPERTS];   // per-wave totals -> per-wave bases
  __shared__ int eoff_s[EXPERTS];
  __shared__ int base_lds[1024 * EXPERTS];  // 32 KB

  int ids[16];
  unsigned long long h64 = 0;
#pragma unroll
  for (int j = 0; j < 16; ++j) {
    ids[j] = top_i[tid * 16 + j];
    h64 += 1ull << (ids[j] * 8);
  }
#pragma unroll
  for (int e = 0; e < EXPERTS; ++e) {
    const int h = (int)((h64 >> (8 * e)) & 0xff);
    int v = h;
    for (int s = 1; s < 64; s <<= 1) {
      const int u = __shfl_up(v, s);
      if (lane >= s) v += u;
    }
    const int excl = v - h;
    const int tot = __shfl(v, 63);
    if (lane == 0) ws[wid][e] = tot;
    base_lds[tid * EXPERTS + e] = excl;
  }
  __syncthreads();
  if (tid == 0) {
    int tot[EXPERTS];
    for (int e = 0; e < EXPERTS; ++e) {
      int run = 0;
      for (int w = 0; w < 16; ++w) { const int c = ws[w][e]; ws[w][e] = run; run += c; }
      tot[e] = run;
    }
    int s = 0, nt = 0;
    for (int e = 0; e < EXPERTS; ++e) {
      eoff_s[e] = s; eoff[e] = s; s += tot[e];
      const int mt = (tot[e] + 127) >> 7;
      for (int i = 0; i < mt; ++i) work[nt++] = (e << 16) | i;
    }
    eoff[EXPERTS] = s;  // == NSLOT
    ntiles[0] = nt;
  }
  __syncthreads();
#pragma unroll
  for (int e = 0; e < EXPERTS; ++e)
    base_lds[tid * EXPERTS + e] += eoff_s[e] + ws[wid][e];
  unsigned long long pre64 = 0;
#pragma unroll
  for (int j = 0; j < 16; ++j) {
    const int entry = tid * 16 + j;
    const int e = ids[j];
    const int pre = (int)((pre64 >> (8 * e)) & 0xff);
    pre64 += 1ull << (8 * e);
    const int s = base_lds[tid * EXPERTS + e] + pre;
    tok_list[s] = entry >> 1;  // token index
    slot_of[entry] = s;
    slot_w[s] = top_w[entry];
  }
}

// ---------------------------------------------------------------------------
// Per-expert GEMM: 128x128 tile, BK=32, mfma_f32_16x16x32_bf16,
// global_load_lds(16B) staging, XOR-swizzled LDS (conflict-free frag reads).
//   C[m][n] = act( sum_k A[row(m)][k] * W[e][n][k] + bias[e][n] )
// GATHER: A row = tok_list[off+m]; COMBINE: fused out += w*val via atomicAdd.
// Work-list grid: blockIdx.y -> (e, mtile) from work[]; blockIdx.x = ntile
// (ntile==blockIdx%8 -> fixed per XCD -> W col-block L2-resident).
template <int GATHER, int LEAKY, int COMBINE>
__global__ __launch_bounds__(256) void moe_gemm(
    const __bf16* __restrict__ A, const int* __restrict__ tok,
    const __bf16* __restrict__ W, const float* __restrict__ bias,
    const int* __restrict__ eoff, const int* __restrict__ work,
    const int* __restrict__ ntiles, const float* __restrict__ slot_w,
    __bf16* __restrict__ outb, float* __restrict__ outf) {
  if ((int)blockIdx.y >= ntiles[0]) return;
  const int wk = work[blockIdx.y];
  const int e = wk >> 16;
  const int m0 = (wk & 0xffff) * 128;
  const int off = eoff[e];
  const int ne = eoff[e + 1] - off;
  const int n0 = blockIdx.x * 128;

  __shared__ __align__(16) __bf16 As[128 * 32];  // [row][k], swizzled chunks
  __shared__ __align__(16) __bf16 Bs[128 * 32];  // [n][k],  swizzled chunks

  const int tid = threadIdx.x;
  const int lane = tid & 63;
  const int wid = tid >> 6;
  const int wm = wid >> 1, wn = wid & 1;
  const int ln = lane & 15, quad = lane >> 4;

  // Staging: chunk c -> tile row c>>2, physical k-slot c&3 holds logical
  // k-chunk kc = (c&3) ^ ((row>>1)&3)  (XOR swizzle).
  const __bf16* aptr[2];
  const __bf16* bptr[2];
  __bf16* alds[2];
  __bf16* blds[2];
#pragma unroll
  for (int j = 0; j < 2; ++j) {
    const int c = (wid * 2 + j) * 64 + lane;  // 0..511
    const int row = c >> 2;
    const int kc = (c & 3) ^ ((row >> 1) & 3);
    int r = m0 + row;
    if (r >= ne) r = m0;  // clamp: garbage rows computed but never stored
    const long arow = GATHER ? (long)tok[off + r] : (long)(off + r);
    aptr[j] = A + arow * DDIM + kc * 8;
    alds[j] = (__bf16*)As + (wid * 2 + j) * 512;
    bptr[j] = W + ((long)e << 20) + (long)(n0 + row) * 1024 + kc * 8;
    blds[j] = (__bf16*)Bs + (wid * 2 + j) * 512;
  }

  // Fragment-read swizzle: logical chunk quad of row r lives at physical
  // slot quad ^ ((r>>1)&3); (r>>1)&3 == (ln>>1)&3 for all our rows.
  const int swz = (quad ^ ((ln >> 1) & 3)) * 8;

  const f32x4_t vzero = {0.f, 0.f, 0.f, 0.f};
  f32x4_t acc[4][4];
#pragma unroll
  for (int i = 0; i < 4; ++i)
#pragma unroll
    for (int j = 0; j < 4; ++j) acc[i][j] = vzero;

  for (int kt = 0; kt < 32; ++kt) {
    const int k0 = kt * 32;
    __syncthreads();  // previous iter's LDS reads done
    gl_lds16(aptr[0] + k0, alds[0]);
    gl_lds16(aptr[1] + k0, alds[1]);
    gl_lds16(bptr[0] + k0, blds[0]);
    gl_lds16(bptr[1] + k0, blds[1]);
    __syncthreads();  // drains vmcnt: staged data visible

    bf16x8_t aF[4], bF[4];
#pragma unroll
    for (int i = 0; i < 4; ++i)
      aF[i] = *(const bf16x8_t*)(As + (wm * 64 + i * 16 + ln) * 32 + swz);
#pragma unroll
    for (int j = 0; j < 4; ++j)
      bF[j] = *(const bf16x8_t*)(Bs + (wn * 64 + j * 16 + ln) * 32 + swz);
#pragma unroll
    for (int i = 0; i < 4; ++i)
#pragma unroll
      for (int j = 0; j < 4; ++j)
        acc[i][j] = __builtin_amdgcn_mfma_f32_16x16x32_bf16(aF[i], bF[j],
                                                            acc[i][j], 0, 0, 0);
  }

  // Epilogue. C/D layout: col = lane&15, row = quad*4 + reg.
  const float* bs = bias + e * 1024;
#pragma unroll
  for (int i = 0; i < 4; ++i) {
    const int rloc = wm * 64 + i * 16 + quad * 4;
#pragma unroll
    for (int j = 0; j < 4; ++j) {
      const int col = n0 + wn * 64 + j * 16 + ln;
      const float bv = bs[col];
#pragma unroll
      for (int r = 0; r < 4; ++r) {
        const int m = m0 + rloc + r;
        if (m < ne) {
          float v = acc[i][j][r] + bv;
          if (LEAKY) v = (v >= 0.f) ? v : 0.01f * v;
          if (COMBINE) {
            const int t = tok[off + m];
            const float w = slot_w[off + m];
            atomicAdd(&outf[(size_t)t * 1024 + col], w * v);
          } else {
            outb[(size_t)(off + m) * 1024 + col] = (__bf16)v;
          }
        }
      }
    }
  }
}

// ---------------------------------------------------------------------------
extern "C" void kernel_launch(void* const* d_in, const int* in_sizes, int n_in,
                              void* d_out, int out_size, void* d_ws,
                              size_t ws_size, hipStream_t stream) {
  (void)in_sizes; (void)n_in; (void)out_size; (void)ws_size;
  const float* x  = (const float*)d_in[0];
  const float* gw = (const float*)d_in[1];
  const float* gb = (const float*)d_in[2];
  const float* w1 = (const float*)d_in[3];
  const float* b1 = (const float*)d_in[4];
  const float* w2 = (const float*)d_in[5];
  const float* b2 = (const float*)d_in[6];
  const float* w3 = (const float*)d_in[7];
  const float* b3 = (const float*)d_in[8];
  float* out = (float*)d_out;

  // Workspace carve-up (~150 MB total).
  uint8_t* p = (uint8_t*)d_ws;
  auto alloc = [&](size_t b) {
    uint8_t* r = p;
    p += (b + 255) & ~(size_t)255;
    return r;
  };
  int*    eoff     = (int*)alloc(4 * (EXPERTS + 1));
  int*    ntiles   = (int*)alloc(4);
  int*    work     = (int*)alloc(4 * MAXTILE);
  int*    top_i    = (int*)alloc(4ull * TOKENS * 2);
  float*  top_w    = (float*)alloc(4ull * TOKENS * 2);
  int*    slot_of  = (int*)alloc(4ull * TOKENS * 2);
  float*  slot_w   = (float*)alloc(4ull * NSLOT);
  int*    tok_list = (int*)alloc(4ull * NSLOT);
  __bf16* xbf      = (__bf16*)alloc(2ull * TOKENS * DDIM);
  __bf16* w1T      = (__bf16*)alloc(2ull * EXPERTS * 1024 * 1024);
  __bf16* w2T      = (__bf16*)alloc(2ull * EXPERTS * 1024 * 1024);
  __bf16* w3T      = (__bf16*)alloc(2ull * EXPERTS * 1024 * 1024);
  __bf16* h1       = (__bf16*)alloc(2ull * NSLOT * 1024);
  __bf16* h2       = (__bf16*)alloc(2ull * NSLOT * 1024);

  // out accumulated via atomics in layer 3 -> zero it (harness poisons 0xAA).
  hipMemsetAsync(out, 0, 4ull * TOKENS * DDIM, stream);

  gate_k<<<TOKENS / 4, 256, 0, stream>>>(x, gw, gb, xbf, top_i, top_w);
  twt_k<<<dim3(16, 32, 24), dim3(32, 8), 0, stream>>>(w1, w2, w3, w1T, w2T, w3T);
  plan_k<<<1, 1024, 0, stream>>>(top_i, top_w, eoff, tok_list, slot_of, slot_w,
                                 work, ntiles);

  moe_gemm<1, 1, 0><<<dim3(8, MAXTILE), 256, 0, stream>>>(
      xbf, tok_list, w1T, b1, eoff, work, ntiles, slot_w, h1, nullptr);
  moe_gemm<0, 1, 0><<<dim3(8, MAXTILE), 256, 0, stream>>>(
      h1, tok_list, w2T, b2, eoff, work, ntiles, slot_w, h2, nullptr);
  moe_gemm<0, 0, 1><<<dim3(8, MAXTILE), 256, 0, stream>>>(
      h2, tok_list, w3T, b3, eoff, work, ntiles, slot_w, nullptr, out);
}

// Round 5
// 437.746 us; speedup vs baseline: 1.1523x; 1.1523x over previous
//
#include <hip/hip_runtime.h>
#include <hip/hip_bf16.h>
#include <stdint.h>

// Problem constants (B=4, T=2048, D=H=1024, E=8, topn=2)
#define TOKENS   8192
#define DDIM     1024
#define EXPERTS  8
#define NSLOT    (TOKENS * 2)   // every token picks exactly 2 experts
#define MAXTILE  136            // >= max sum over e of ceil(ne/128) (135)

typedef __bf16 bf16x8_t __attribute__((ext_vector_type(8)));
typedef __bf16 bf16x4_t __attribute__((ext_vector_type(4)));
typedef float  f32x4_t  __attribute__((ext_vector_type(4)));

// ---------------------------------------------------------------------------
// async global->LDS, 16B per lane; LDS dest is wave-uniform base (HW adds
// lane*16).
__device__ __forceinline__ void gl_lds16(const void* g, void* l) {
  __builtin_amdgcn_global_load_lds(
      (const __attribute__((address_space(1))) void*)g,
      (__attribute__((address_space(3))) void*)l, 16, 0, 0);
}

// ---------------------------------------------------------------------------
// Weight transpose + convert for all 3 layers: w[e][k][n] fp32 -> wT[e][n][k]
// bf16. z = 24 (layer = z>>3, expert = z&7).
__global__ void twt_k(const float* __restrict__ w1, const float* __restrict__ w2,
                      const float* __restrict__ w3, __bf16* __restrict__ w1T,
                      __bf16* __restrict__ w2T, __bf16* __restrict__ w3T) {
  __shared__ float tile[64][33];
  const int layer = blockIdx.z >> 3, e = blockIdx.z & 7;
  const float* w = (layer == 0) ? w1 : (layer == 1) ? w2 : w3;
  __bf16* wT = (layer == 0) ? w1T : (layer == 1) ? w2T : w3T;
  const int kb = blockIdx.x * 64, nb = blockIdx.y * 32;
  const size_t ebase = (size_t)e << 20;  // e * 1024*1024
  const int tx = threadIdx.x, ty = threadIdx.y;  // 32 x 8
  const float* src = w + ebase;
#pragma unroll
  for (int r = ty; r < 64; r += 8)
    tile[r][tx] = src[(size_t)(kb + r) * 1024 + nb + tx];
  __syncthreads();
  __bf16* dst = wT + ebase;
#pragma unroll
  for (int r = ty; r < 32; r += 8) {
    union { __bf16 h[2]; unsigned u; } pk;
    pk.h[0] = (__bf16)tile[2 * tx][r];
    pk.h[1] = (__bf16)tile[2 * tx + 1][r];
    *(unsigned*)(dst + (size_t)(nb + r) * 1024 + kb + 2 * tx) = pk.u;
  }
}

// ---------------------------------------------------------------------------
// Gating + x->bf16 convert fused: one wave per token, no atomics.
// Weights = softmax over the two top logits (L1-renorm cancels denominator).
__global__ __launch_bounds__(256) void gate_k(
    const float* __restrict__ x, const float* __restrict__ gw,
    const float* __restrict__ gb, __bf16* __restrict__ xbf,
    int* __restrict__ top_i, float* __restrict__ top_w) {
  const int t = blockIdx.x * 4 + (threadIdx.x >> 6);
  const int lane = threadIdx.x & 63;
  const float4* x4 = (const float4*)(x + (size_t)t * DDIM);
  bf16x4_t* xo4 = (bf16x4_t*)(xbf + (size_t)t * DDIM);
  const float4* g4 = (const float4*)gw;
  float acc[EXPERTS];
#pragma unroll
  for (int e = 0; e < EXPERTS; ++e) acc[e] = 0.f;
#pragma unroll
  for (int d4 = lane; d4 < 256; d4 += 64) {
    const float4 v = x4[d4];
    bf16x4_t o = {(__bf16)v.x, (__bf16)v.y, (__bf16)v.z, (__bf16)v.w};
    xo4[d4] = o;
    const float4* g = g4 + (size_t)d4 * 8;  // rows 4*d4..4*d4+3, 2 float4 each
    float4 ga, gbv;
    ga = g[0]; gbv = g[1];
    acc[0] += v.x * ga.x; acc[1] += v.x * ga.y; acc[2] += v.x * ga.z; acc[3] += v.x * ga.w;
    acc[4] += v.x * gbv.x; acc[5] += v.x * gbv.y; acc[6] += v.x * gbv.z; acc[7] += v.x * gbv.w;
    ga = g[2]; gbv = g[3];
    acc[0] += v.y * ga.x; acc[1] += v.y * ga.y; acc[2] += v.y * ga.z; acc[3] += v.y * ga.w;
    acc[4] += v.y * gbv.x; acc[5] += v.y * gbv.y; acc[6] += v.y * gbv.z; acc[7] += v.y * gbv.w;
    ga = g[4]; gbv = g[5];
    acc[0] += v.z * ga.x; acc[1] += v.z * ga.y; acc[2] += v.z * ga.z; acc[3] += v.z * ga.w;
    acc[4] += v.z * gbv.x; acc[5] += v.z * gbv.y; acc[6] += v.z * gbv.z; acc[7] += v.z * gbv.w;
    ga = g[6]; gbv = g[7];
    acc[0] += v.w * ga.x; acc[1] += v.w * ga.y; acc[2] += v.w * ga.z; acc[3] += v.w * ga.w;
    acc[4] += v.w * gbv.x; acc[5] += v.w * gbv.y; acc[6] += v.w * gbv.z; acc[7] += v.w * gbv.w;
  }
#pragma unroll
  for (int e = 0; e < EXPERTS; ++e)
    for (int s = 32; s > 0; s >>= 1) acc[e] += __shfl_down(acc[e], s);
  if (lane == 0) {
#pragma unroll
    for (int e = 0; e < EXPERTS; ++e) acc[e] += gb[e];
    int i1 = 0;
    for (int e = 1; e < EXPERTS; ++e)
      if (acc[e] > acc[i1]) i1 = e;
    int i2 = (i1 == 0) ? 1 : 0;
    for (int e = 0; e < EXPERTS; ++e)
      if (e != i1 && acc[e] > acc[i2]) i2 = e;
    const float r = expf(acc[i2] - acc[i1]);  // <= 1
    const float wA = 1.f / (1.f + r);
    const float wB = r / (1.f + r);
    top_i[t * 2] = i1; top_i[t * 2 + 1] = i2;
    top_w[t * 2] = wA; top_w[t * 2 + 1] = wB;
  }
}

// ---------------------------------------------------------------------------
// Routing plan: ONE block, 1024 threads. Stable counting-sort of the 16384
// (token,expert) entries; zero global atomics, deterministic. Also emits the
// exact GEMM tile work-list ((e,mtile) pairs).
__global__ __launch_bounds__(1024) void plan_k(
    const int* __restrict__ top_i, int* __restrict__ eoff,
    int* __restrict__ tok_list, int* __restrict__ slot_of,
    int* __restrict__ work, int* __restrict__ ntiles) {
  const int tid = threadIdx.x;
  const int lane = tid & 63, wid = tid >> 6;  // 16 waves
  __shared__ int ws[16][EXPERTS];   // per-wave totals -> per-wave bases
  __shared__ int eoff_s[EXPERTS];
  __shared__ int base_lds[1024 * EXPERTS];  // 32 KB

  int ids[16];
  unsigned long long h64 = 0;
#pragma unroll
  for (int j = 0; j < 16; ++j) {
    ids[j] = top_i[tid * 16 + j];
    h64 += 1ull << (ids[j] * 8);
  }
#pragma unroll
  for (int e = 0; e < EXPERTS; ++e) {
    const int h = (int)((h64 >> (8 * e)) & 0xff);
    int v = h;
    for (int s = 1; s < 64; s <<= 1) {
      const int u = __shfl_up(v, s);
      if (lane >= s) v += u;
    }
    const int excl = v - h;
    const int tot = __shfl(v, 63);
    if (lane == 0) ws[wid][e] = tot;
    base_lds[tid * EXPERTS + e] = excl;
  }
  __syncthreads();
  if (tid == 0) {
    int tot[EXPERTS];
    for (int e = 0; e < EXPERTS; ++e) {
      int run = 0;
      for (int w = 0; w < 16; ++w) { const int c = ws[w][e]; ws[w][e] = run; run += c; }
      tot[e] = run;
    }
    int s = 0, nt = 0;
    for (int e = 0; e < EXPERTS; ++e) {
      eoff_s[e] = s; eoff[e] = s; s += tot[e];
      const int mt = (tot[e] + 127) >> 7;
      for (int i = 0; i < mt; ++i) work[nt++] = (e << 16) | i;
    }
    eoff[EXPERTS] = s;  // == NSLOT
    ntiles[0] = nt;
  }
  __syncthreads();
#pragma unroll
  for (int e = 0; e < EXPERTS; ++e)
    base_lds[tid * EXPERTS + e] += eoff_s[e] + ws[wid][e];
  unsigned long long pre64 = 0;
#pragma unroll
  for (int j = 0; j < 16; ++j) {
    const int entry = tid * 16 + j;
    const int e = ids[j];
    const int pre = (int)((pre64 >> (8 * e)) & 0xff);
    pre64 += 1ull << (8 * e);
    const int s = base_lds[tid * EXPERTS + e] + pre;
    tok_list[s] = entry >> 1;  // token index
    slot_of[entry] = s;
  }
}

// ---------------------------------------------------------------------------
// Per-expert GEMM: 128x128 tile, BK=32, mfma_f32_16x16x32_bf16,
// global_load_lds(16B) staging, XOR-swizzled LDS (conflict-free frag reads).
//   C[m][n] = act( sum_k A[row(m)][k] * W[e][n][k] + bias[e][n] )  -> bf16
// GATHER: A row = tok_list[off+m]; else off+m.
// Grid: blockIdx.x = ntile (0..7) -> fixed per XCD -> 2MB W col L2-resident;
// blockIdx.y -> (e, mtile) from work[].
template <int GATHER, int LEAKY>
__global__ __launch_bounds__(256) void moe_gemm(
    const __bf16* __restrict__ A, const int* __restrict__ tok,
    const __bf16* __restrict__ W, const float* __restrict__ bias,
    const int* __restrict__ eoff, const int* __restrict__ work,
    const int* __restrict__ ntiles, __bf16* __restrict__ out) {
  if ((int)blockIdx.y >= ntiles[0]) return;
  const int wk = work[blockIdx.y];
  const int e = wk >> 16;
  const int m0 = (wk & 0xffff) * 128;
  const int off = eoff[e];
  const int ne = eoff[e + 1] - off;
  const int n0 = blockIdx.x * 128;

  __shared__ __align__(16) __bf16 As[128 * 32];  // [row][k], swizzled chunks
  __shared__ __align__(16) __bf16 Bs[128 * 32];  // [n][k],  swizzled chunks

  const int tid = threadIdx.x;
  const int lane = tid & 63;
  const int wid = tid >> 6;
  const int wm = wid >> 1, wn = wid & 1;
  const int ln = lane & 15, quad = lane >> 4;

  // Staging: chunk c -> tile row c>>2, physical k-slot c&3 holds logical
  // k-chunk kc = (c&3) ^ ((row>>1)&3)  (XOR swizzle).
  const __bf16* aptr[2];
  const __bf16* bptr[2];
  __bf16* alds[2];
  __bf16* blds[2];
#pragma unroll
  for (int j = 0; j < 2; ++j) {
    const int c = (wid * 2 + j) * 64 + lane;  // 0..511
    const int row = c >> 2;
    const int kc = (c & 3) ^ ((row >> 1) & 3);
    int r = m0 + row;
    if (r >= ne) r = m0;  // clamp: garbage rows computed but never stored
    const long arow = GATHER ? (long)tok[off + r] : (long)(off + r);
    aptr[j] = A + arow * DDIM + kc * 8;
    alds[j] = (__bf16*)As + (wid * 2 + j) * 512;
    bptr[j] = W + ((long)e << 20) + (long)(n0 + row) * 1024 + kc * 8;
    blds[j] = (__bf16*)Bs + (wid * 2 + j) * 512;
  }

  // Fragment-read swizzle: logical chunk quad of row r lives at physical
  // slot quad ^ ((r>>1)&3); (r>>1)&3 == (ln>>1)&3 for all our rows.
  const int swz = (quad ^ ((ln >> 1) & 3)) * 8;

  const f32x4_t vzero = {0.f, 0.f, 0.f, 0.f};
  f32x4_t acc[4][4];
#pragma unroll
  for (int i = 0; i < 4; ++i)
#pragma unroll
    for (int j = 0; j < 4; ++j) acc[i][j] = vzero;

  for (int kt = 0; kt < 32; ++kt) {
    const int k0 = kt * 32;
    __syncthreads();  // previous iter's LDS reads done
    gl_lds16(aptr[0] + k0, alds[0]);
    gl_lds16(aptr[1] + k0, alds[1]);
    gl_lds16(bptr[0] + k0, blds[0]);
    gl_lds16(bptr[1] + k0, blds[1]);
    __syncthreads();  // drains vmcnt: staged data visible

    bf16x8_t aF[4], bF[4];
#pragma unroll
    for (int i = 0; i < 4; ++i)
      aF[i] = *(const bf16x8_t*)(As + (wm * 64 + i * 16 + ln) * 32 + swz);
#pragma unroll
    for (int j = 0; j < 4; ++j)
      bF[j] = *(const bf16x8_t*)(Bs + (wn * 64 + j * 16 + ln) * 32 + swz);
#pragma unroll
    for (int i = 0; i < 4; ++i)
#pragma unroll
      for (int j = 0; j < 4; ++j)
        acc[i][j] = __builtin_amdgcn_mfma_f32_16x16x32_bf16(aF[i], bF[j],
                                                            acc[i][j], 0, 0, 0);
  }

  // Epilogue. C/D layout: col = lane&15, row = quad*4 + reg.
  const float* bs = bias + e * 1024;
#pragma unroll
  for (int i = 0; i < 4; ++i) {
    const int rloc = wm * 64 + i * 16 + quad * 4;
#pragma unroll
    for (int j = 0; j < 4; ++j) {
      const int col = n0 + wn * 64 + j * 16 + ln;
      const float bv = bs[col];
#pragma unroll
      for (int r = 0; r < 4; ++r) {
        const int m = m0 + rloc + r;
        if (m < ne) {
          float v = acc[i][j][r] + bv;
          if (LEAKY) v = (v >= 0.f) ? v : 0.01f * v;
          out[(size_t)(off + m) * 1024 + col] = (__bf16)v;
        }
      }
    }
  }
}

// ---------------------------------------------------------------------------
// Final combine: out[t] = wA*eo[slotA] + wB*eo[slotB]  (eo is bf16)
__global__ __launch_bounds__(256) void combine_k(
    const __bf16* __restrict__ eo, const int* __restrict__ slot_of,
    const float* __restrict__ top_w, float* __restrict__ out) {
  const int t = blockIdx.x;
  const int s1 = slot_of[t * 2], s2 = slot_of[t * 2 + 1];
  const float w1 = top_w[t * 2], w2 = top_w[t * 2 + 1];
  const bf16x4_t a = ((const bf16x4_t*)(eo + (size_t)s1 * DDIM))[threadIdx.x];
  const bf16x4_t b = ((const bf16x4_t*)(eo + (size_t)s2 * DDIM))[threadIdx.x];
  float4 o;
  o.x = w1 * (float)a[0] + w2 * (float)b[0];
  o.y = w1 * (float)a[1] + w2 * (float)b[1];
  o.z = w1 * (float)a[2] + w2 * (float)b[2];
  o.w = w1 * (float)a[3] + w2 * (float)b[3];
  ((float4*)(out + (size_t)t * DDIM))[threadIdx.x] = o;
}

// ---------------------------------------------------------------------------
extern "C" void kernel_launch(void* const* d_in, const int* in_sizes, int n_in,
                              void* d_out, int out_size, void* d_ws,
                              size_t ws_size, hipStream_t stream) {
  (void)in_sizes; (void)n_in; (void)out_size; (void)ws_size;
  const float* x  = (const float*)d_in[0];
  const float* gw = (const float*)d_in[1];
  const float* gb = (const float*)d_in[2];
  const float* w1 = (const float*)d_in[3];
  const float* b1 = (const float*)d_in[4];
  const float* w2 = (const float*)d_in[5];
  const float* b2 = (const float*)d_in[6];
  const float* w3 = (const float*)d_in[7];
  const float* b3 = (const float*)d_in[8];
  float* out = (float*)d_out;

  // Workspace carve-up (~150 MB total).
  uint8_t* p = (uint8_t*)d_ws;
  auto alloc = [&](size_t b) {
    uint8_t* r = p;
    p += (b + 255) & ~(size_t)255;
    return r;
  };
  int*    eoff     = (int*)alloc(4 * (EXPERTS + 1));
  int*    ntiles   = (int*)alloc(4);
  int*    work     = (int*)alloc(4 * MAXTILE);
  int*    top_i    = (int*)alloc(4ull * TOKENS * 2);
  float*  top_w    = (float*)alloc(4ull * TOKENS * 2);
  int*    slot_of  = (int*)alloc(4ull * TOKENS * 2);
  int*    tok_list = (int*)alloc(4ull * NSLOT);
  __bf16* xbf      = (__bf16*)alloc(2ull * TOKENS * DDIM);
  __bf16* w1T      = (__bf16*)alloc(2ull * EXPERTS * 1024 * 1024);
  __bf16* w2T      = (__bf16*)alloc(2ull * EXPERTS * 1024 * 1024);
  __bf16* w3T      = (__bf16*)alloc(2ull * EXPERTS * 1024 * 1024);
  __bf16* h1       = (__bf16*)alloc(2ull * NSLOT * 1024);
  __bf16* h2       = (__bf16*)alloc(2ull * NSLOT * 1024);
  __bf16* eo       = (__bf16*)alloc(2ull * NSLOT * 1024);

  gate_k<<<TOKENS / 4, 256, 0, stream>>>(x, gw, gb, xbf, top_i, top_w);
  twt_k<<<dim3(16, 32, 24), dim3(32, 8), 0, stream>>>(w1, w2, w3, w1T, w2T, w3T);
  plan_k<<<1, 1024, 0, stream>>>(top_i, eoff, tok_list, slot_of, work, ntiles);

  moe_gemm<1, 1><<<dim3(8, MAXTILE), 256, 0, stream>>>(
      xbf, tok_list, w1T, b1, eoff, work, ntiles, h1);
  moe_gemm<0, 1><<<dim3(8, MAXTILE), 256, 0, stream>>>(
      h1, tok_list, w2T, b2, eoff, work, ntiles, h2);
  moe_gemm<0, 0><<<dim3(8, MAXTILE), 256, 0, stream>>>(
      h2, tok_list, w3T, b3, eoff, work, ntiles, eo);

  combine_k<<<TOKENS, 256, 0, stream>>>(eo, slot_of, top_w, out);
}